// Round 10
// baseline (232.163 us; speedup 1.0000x reference)
//
#include <hip/hip_runtime.h>
#include <stdint.h>

#define B_  4
#define T_  2048
#define D_  1024
#define H_  16
#define HD_ 64
#define KK_ 1024

typedef __bf16 bf16_t;
typedef __bf16 bf16x8 __attribute__((ext_vector_type(8)));
typedef float  f32x4  __attribute__((ext_vector_type(4)));
typedef float  f32x16 __attribute__((ext_vector_type(16)));

__device__ __forceinline__ uint16_t f2bf(float f) {
  uint32_t x = __float_as_uint(f);
  uint32_t r = (x + 0x7fffu + ((x >> 16) & 1u)) >> 16;
  return (uint16_t)r;
}

__device__ __forceinline__ uint32_t pack2(float a, float b) {
  return (uint32_t)f2bf(a) | ((uint32_t)f2bf(b) << 16);
}

__device__ __forceinline__ float exp2a(float x) {
  float r;
  asm("v_exp_f32 %0, %1" : "=v"(r) : "v"(x));
  return r;
}

__device__ __forceinline__ uint32_t cvtpk(float a, float b) {
  uint32_t r;
  asm("v_cvt_pk_bf16_f32 %0, %1, %2" : "=v"(r) : "v"(a), "v"(b));
  return r;
}

__device__ __forceinline__ void plswap(uint32_t& a, uint32_t& b) {
  asm("v_permlane32_swap_b32 %0, %1" : "+v"(a), "+v"(b));
}

// async 16B global->LDS; lds dst is wave-uniform base (+lane*16 by HW)
__device__ __forceinline__ void gll16(const void* g, void* l) {
  __builtin_amdgcn_global_load_lds(
      (const __attribute__((address_space(1))) void*)g,
      (__attribute__((address_space(3))) void*)l, 16, 0, 0);
}

// ---------------- fp32 -> bf16 conversion ----------------
__global__ __launch_bounds__(256) void cvt3(const float* __restrict__ s0,
                                            const float* __restrict__ s1,
                                            const float* __restrict__ s2,
                                            uint16_t* __restrict__ d0,
                                            uint16_t* __restrict__ d1,
                                            uint16_t* __restrict__ d2) {
  const float* in = blockIdx.y == 0 ? s0 : (blockIdx.y == 1 ? s1 : s2);
  uint16_t* out = blockIdx.y == 0 ? d0 : (blockIdx.y == 1 ? d1 : d2);
  int i = (blockIdx.x * 256 + threadIdx.x) * 8;
  float4 a = *(const float4*)(in + i);
  float4 b = *(const float4*)(in + i + 4);
  uint4 u;
  u.x = pack2(a.x, a.y);
  u.y = pack2(a.z, a.w);
  u.z = pack2(b.x, b.y);
  u.w = pack2(b.z, b.w);
  *(uint4*)(out + i) = u;
}

__global__ __launch_bounds__(256) void cvtW(const float* __restrict__ s0,
                                            const float* __restrict__ s1,
                                            const float* __restrict__ s2,
                                            const float* __restrict__ s3,
                                            uint16_t* __restrict__ d0,
                                            uint16_t* __restrict__ d1,
                                            uint16_t* __restrict__ d2,
                                            uint16_t* __restrict__ d3) {
  const float* in = blockIdx.y == 0 ? s0 : (blockIdx.y == 1 ? s1 :
                    (blockIdx.y == 2 ? s2 : s3));
  uint16_t* out = blockIdx.y == 0 ? d0 : (blockIdx.y == 1 ? d1 :
                  (blockIdx.y == 2 ? d2 : d3));
  int i = (blockIdx.x * 256 + threadIdx.x) * 8;
  float4 a = *(const float4*)(in + i);
  float4 b = *(const float4*)(in + i + 4);
  uint4 u;
  u.x = pack2(a.x, a.y);
  u.y = pack2(a.z, a.w);
  u.z = pack2(b.x, b.y);
  u.w = pack2(b.z, b.w);
  *(uint4*)(out + i) = u;
}

// ---------------- GEMM: C = A[M,K] @ W[N,K]^T, m97-style multi-block ----------------
// 128x128 tile, 4 waves (2x2), 64x64/wave, BK=64.
// A: LDS double buffer (32KB total) via global_load_lds, stage-1-ahead.
// B: registers, double-set, loaded 1 tile ahead direct from global (L2-resident W).
// Seam: vmcnt(8) (A's 4 gll16 drained; 8 B loads flying) + barrier.
// mode 0: Q -> bf16 [B,H,T,64] scaled; 1: K same; 2: V -> [B,H,64,T]; 3: fp32.
__global__ __launch_bounds__(256, 2)
void gemmBR(const uint16_t* __restrict__ a0, const uint16_t* __restrict__ a1,
            const uint16_t* __restrict__ a2, const uint16_t* __restrict__ w0,
            const uint16_t* __restrict__ w1, const uint16_t* __restrict__ w2,
            void* __restrict__ o0, void* __restrict__ o1, void* __restrict__ o2,
            int mode_base, float scale0) {
  __shared__ __align__(16) uint16_t Ab[2][128 * 64];  // 32 KB

  const int nwg = gridDim.x;
  const int bid = blockIdx.x;
  const int cpx = nwg >> 3;                       // nwg % 8 == 0
  const int swz = (bid & 7) * cpx + (bid >> 3);   // XCD-contiguous chunks
  const int g = swz >> 9;                         // 512 blocks per gemm
  const int r = swz & 511;
  const int mt = r >> 3, nt = r & 7;
  const int m0 = mt * 128, n0 = nt * 128;

  const uint16_t* A = g == 0 ? a0 : (g == 1 ? a1 : a2);
  const uint16_t* W = g == 0 ? w0 : (g == 1 ? w1 : w2);
  void* Out = g == 0 ? o0 : (g == 1 ? o1 : o2);
  const int mode = mode_base + g;
  const float scale = (mode == 0) ? scale0 : 1.0f;

  const int tid = threadIdx.x;
  const int wid = tid >> 6, lane = tid & 63;
  const int fr = lane & 15, fq = lane >> 4;
  const int wm = wid >> 1, wn = wid & 1;
  const int srow = lane >> 3, c8 = lane & 7;

  f32x4 acc[4][4];
#pragma unroll
  for (int i = 0; i < 4; ++i)
#pragma unroll
    for (int j = 0; j < 4; ++j) acc[i][j] = (f32x4){0.f, 0.f, 0.f, 0.f};

  const int NT = KK_ / 64;  // 16 tiles (even)
  bf16x8 bfA[4][2], bfB[4][2];  // B fragment double-set (registers)

  // LDS row = 64 elems (8 chunks of 8); LDS[row][j] = src[row][j ^ (row&7)].
#define STAGEA(s, t)                                                          \
  do {                                                                        \
    _Pragma("unroll")                                                         \
    for (int c = 0; c < 4; ++c) {                                             \
      int row = wid * 32 + c * 8 + srow;                                      \
      int sw = (c8 ^ (row & 7)) << 3;                                         \
      gll16(A + (size_t)(m0 + row) * KK_ + (t) * 64 + sw,                     \
            &Ab[s][(wid * 32 + c * 8) * 64]);                                 \
    }                                                                         \
  } while (0)

  // wave's B cols: n0 + wn*64 .. +64; frag (nf, ks): row n0+wn*64+nf*16+fr,
  // k-offset (ks*4+fq)*8 -> 16B contiguous per lane, L2-served.
#define BLOAD(bf, t)                                                          \
  do {                                                                        \
    _Pragma("unroll")                                                         \
    for (int nf = 0; nf < 4; ++nf)                                            \
      _Pragma("unroll")                                                       \
      for (int ks = 0; ks < 2; ++ks)                                          \
        bf[nf][ks] = *(const bf16x8*)(W +                                     \
            (size_t)(n0 + wn * 64 + nf * 16 + fr) * KK_ + (t) * 64 +          \
            (ks * 4 + fq) * 8);                                               \
  } while (0)

  // prologue: stage A0, load B0; wait A0 (B0 waited by compiler at first use)
  STAGEA(0, 0);
  __builtin_amdgcn_sched_barrier(0);
  BLOAD(bfA, 0);
  __builtin_amdgcn_sched_barrier(0);
  asm volatile("s_waitcnt vmcnt(8)" ::: "memory");
  __builtin_amdgcn_s_barrier();

  // BODY(t): issue A(t+1)->LDS, B(t+1)->bfL; read A frags; MFMA with bfU;
  // seam vmcnt(8)+barrier.
#define BODY(t, bfU, bfL)                                                     \
  do {                                                                        \
    if ((t) + 1 < NT) {                                                       \
      STAGEA(((t) + 1) & 1, (t) + 1);                                         \
      __builtin_amdgcn_sched_barrier(0);                                      \
      BLOAD(bfL, (t) + 1);                                                    \
      __builtin_amdgcn_sched_barrier(0);                                      \
    }                                                                         \
    const uint16_t* Ac = &Ab[(t) & 1][0];                                     \
    bf16x8 af[4][2];                                                          \
    _Pragma("unroll")                                                         \
    for (int mf = 0; mf < 4; ++mf) {                                          \
      int ra = wm * 64 + mf * 16 + fr;                                        \
      _Pragma("unroll")                                                       \
      for (int ks = 0; ks < 2; ++ks)                                          \
        af[mf][ks] =                                                          \
            *(const bf16x8*)&Ac[ra * 64 + (((ks * 4 + fq) ^ (ra & 7)) << 3)]; \
    }                                                                         \
    __builtin_amdgcn_s_setprio(1);                                            \
    _Pragma("unroll")                                                         \
    for (int ks = 0; ks < 2; ++ks)                                            \
      _Pragma("unroll")                                                       \
      for (int mf = 0; mf < 4; ++mf)                                          \
        _Pragma("unroll")                                                     \
        for (int nf = 0; nf < 4; ++nf)                                        \
          acc[mf][nf] = __builtin_amdgcn_mfma_f32_16x16x32_bf16(              \
              af[mf][ks], bfU[nf][ks], acc[mf][nf], 0, 0, 0);                 \
    __builtin_amdgcn_s_setprio(0);                                            \
    if ((t) + 1 < NT) {                                                       \
      asm volatile("s_waitcnt vmcnt(8)" ::: "memory"); /* A(t+1) landed */    \
      __builtin_amdgcn_s_barrier();                                           \
    }                                                                         \
  } while (0)

  for (int tt = 0; tt < NT; tt += 2) {
    BODY(tt, bfA, bfB);
    BODY(tt + 1, bfB, bfA);
  }
#undef BODY
#undef BLOAD
#undef STAGEA

  // epilogue
#pragma unroll
  for (int mf = 0; mf < 4; ++mf) {
#pragma unroll
    for (int nf = 0; nf < 4; ++nf) {
      int m = m0 + wm * 64 + mf * 16 + fq * 4;
      int n = n0 + wn * 64 + nf * 16 + fr;
      if (mode == 2) {
        int b = m >> 11, t = m & (T_ - 1);
        int h = n >> 6, hd = n & 63;
        uint2 pk;
        pk.x = pack2(acc[mf][nf][0], acc[mf][nf][1]);
        pk.y = pack2(acc[mf][nf][2], acc[mf][nf][3]);
        uint16_t* dst = (uint16_t*)Out + ((((size_t)b * H_ + h) * HD_ + hd) * T_ + t);
        *(uint2*)dst = pk;
      } else if (mode == 3) {
#pragma unroll
        for (int rr = 0; rr < 4; ++rr)
          ((float*)Out)[(size_t)(m + rr) * D_ + n] = acc[mf][nf][rr];
      } else {
#pragma unroll
        for (int rr = 0; rr < 4; ++rr) {
          int mm = m + rr;
          int b = mm >> 11, t = mm & (T_ - 1);
          int h = n >> 6, hd = n & 63;
          ((uint16_t*)Out)[((((size_t)b * H_ + h) * T_ + t) << 6) + hd] =
              f2bf(acc[mf][nf][rr] * scale);
        }
      }
    }
  }
}

// ---------------- flash attention (causal), 8 waves x 32 q, 32x32 swapped ----------------
// Triple-buffered K/V, counted vmcnt(2), longest-first grid.
// Qh,Kh: [B,H,T,64] bf16 (Q pre-scaled by 0.125*log2e). Vt: [B,H,64,T] bf16.
__global__ __launch_bounds__(512)
void attn_fwd(const uint16_t* __restrict__ Qh, const uint16_t* __restrict__ Kh,
              const uint16_t* __restrict__ Vt, uint16_t* __restrict__ O) {
  // SB[0..2] = K triple buffer, SB[3..5] = V triple buffer (48 KB).
  __shared__ __align__(16) uint16_t SB[6][64 * 64];

  const int tid = threadIdx.x, wid = tid >> 6, lane = tid & 63;
  const int ql = lane & 31, hi = lane >> 5;
  const int bid = blockIdx.x;
  const int qb = (T_ / 256 - 1) - (bid >> 6);  // longest blocks first
  const int bh = bid & 63;
  const int q0 = qb * 256;
  const int wq0 = q0 + wid * 32;  // this wave's first q row
  const size_t hoff = (size_t)bh * T_ * HD_;
  const uint16_t* Qp = Qh + hoff;
  const uint16_t* Kp = Kh + hoff;
  const uint16_t* Vp = Vt + hoff;

  // Q fragments (B-operand): lane owns q-row (wq0+ql); k = hd = ks*16 + hi*8 + j
  bf16x8 qf[4];
  {
    const uint16_t* qrow = Qp + (size_t)(wq0 + ql) * 64 + hi * 8;
#pragma unroll
    for (int ks = 0; ks < 4; ++ks) qf[ks] = *(const bf16x8*)(qrow + ks * 16);
  }

  float m = -1e30f, l = 0.f;
  f32x16 acc[2];  // O^T: row = hd = mo*32 + (r&3)+8*(r>>2)+4*hi, col = q = ql
#pragma unroll
  for (int mo = 0; mo < 2; ++mo)
#pragma unroll
    for (int r = 0; r < 16; ++r) acc[mo][r] = 0.f;

  const int ntiles = 4 * qb + 4;

#define STAGE(buf, t)                                                        \
  do {                                                                       \
    int row = wid * 8 + (lane >> 3);                                         \
    int sw = ((lane & 7) ^ (row & 7)) << 3;                                  \
    gll16(Kp + (size_t)((t) * 64 + row) * 64 + sw, &SB[buf][wid * 512]);     \
    gll16(Vp + (size_t)row * T_ + (t) * 64 + sw, &SB[3 + (buf)][wid * 512]); \
  } while (0)

  STAGE(0, 0);
  if (ntiles > 1) STAGE(1, 1);
  asm volatile("s_waitcnt vmcnt(2)" ::: "memory");
  __builtin_amdgcn_s_barrier();

  int cur = 0;
  for (int it = 0; it < ntiles; ++it) {
    if (it + 2 < ntiles) {
      int nb = cur + 2; if (nb >= 3) nb -= 3;
      STAGE(nb, it + 2);
    }

    if (it * 64 <= wq0 + 31) {  // wave active unless whole tile above diagonal
      // S^T = K @ Q : col = q (lane-local), rows = kv
      f32x16 st[2];
#pragma unroll
      for (int mm = 0; mm < 2; ++mm)
#pragma unroll
        for (int r = 0; r < 16; ++r) st[mm][r] = 0.f;
#pragma unroll
      for (int ks = 0; ks < 4; ++ks) {
#pragma unroll
        for (int mm = 0; mm < 2; ++mm) {
          int row = mm * 32 + ql;
          int ch = (ks * 2 + hi) ^ (row & 7);
          bf16x8 kf = *(const bf16x8*)&SB[cur][row * 64 + ch * 8];
          st[mm] = __builtin_amdgcn_mfma_f32_32x32x16_bf16(kf, qf[ks], st[mm], 0, 0, 0);
        }
      }

      // causal mask (diagonal-straddling tiles only)
      if (it * 64 + 63 > wq0) {
        int qg = wq0 + ql;
#pragma unroll
        for (int mm = 0; mm < 2; ++mm)
#pragma unroll
          for (int r = 0; r < 16; ++r) {
            int kv = it * 64 + mm * 32 + (r & 3) + 8 * (r >> 2) + 4 * hi;
            if (kv > qg) st[mm][r] = -1e30f;
          }
      }

      // row max: 32 in-lane + pair lane
      float pm = st[0][0];
#pragma unroll
      for (int r = 1; r < 16; ++r) pm = fmaxf(pm, st[0][r]);
#pragma unroll
      for (int r = 0; r < 16; ++r) pm = fmaxf(pm, st[1][r]);
      pm = fmaxf(pm, __shfl_xor(pm, 32));

      // defer-max rescale (THR = 8 in log2 domain)
      if (__any(pm > m + 8.f)) {
        float mn = fmaxf(m, pm);
        float sf = exp2a(m - mn);
        m = mn;
        l *= sf;
#pragma unroll
        for (int mo = 0; mo < 2; ++mo)
#pragma unroll
          for (int r = 0; r < 16; ++r) acc[mo][r] *= sf;
      }

      // P = exp2(S - m), row sum
      float rs = 0.f;
#pragma unroll
      for (int mm = 0; mm < 2; ++mm)
#pragma unroll
        for (int r = 0; r < 16; ++r) {
          float p = exp2a(st[mm][r] - m);
          st[mm][r] = p;
          rs += p;
        }
      rs += __shfl_xor(rs, 32);
      l += rs;

      // P -> bf16 B-frags in-register (cvt_pk + permlane32_swap)
      bf16x8 pf[4];
#pragma unroll
      for (int mm = 0; mm < 2; ++mm)
#pragma unroll
        for (int g = 0; g < 2; ++g) {
          uint32_t a1 = cvtpk(st[mm][8 * g + 0], st[mm][8 * g + 1]);
          uint32_t a2 = cvtpk(st[mm][8 * g + 2], st[mm][8 * g + 3]);
          uint32_t b1 = cvtpk(st[mm][8 * g + 4], st[mm][8 * g + 5]);
          uint32_t b2 = cvtpk(st[mm][8 * g + 6], st[mm][8 * g + 7]);
          plswap(a1, b1);
          plswap(a2, b2);
          union { uint32_t w[4]; bf16x8 v; } u;
          u.w[0] = a1; u.w[1] = a2; u.w[2] = b1; u.w[3] = b2;
          pf[mm * 2 + g] = u.v;
        }

      // O^T += V^T @ P^T
#pragma unroll
      for (int ks = 0; ks < 4; ++ks) {
#pragma unroll
        for (int mo = 0; mo < 2; ++mo) {
          int row = mo * 32 + ql;
          int ch = (ks * 2 + hi) ^ (row & 7);
          bf16x8 vf = *(const bf16x8*)&SB[3 + cur][row * 64 + ch * 8];
          acc[mo] = __builtin_amdgcn_mfma_f32_32x32x16_bf16(vf, pf[ks], acc[mo], 0, 0, 0);
        }
      }
    }

    if (it + 1 < ntiles) {
      if (it + 2 < ntiles) {
        asm volatile("s_waitcnt vmcnt(2)" ::: "memory");  // it+1 landed, it+2 flying
      } else {
        asm volatile("s_waitcnt vmcnt(0)" ::: "memory");  // tail
      }
      __builtin_amdgcn_s_barrier();
    }
    ++cur; if (cur == 3) cur = 0;
  }
#undef STAGE

  // epilogue: O^T -> LDS (transpose, swizzled) -> coalesced global store
  __syncthreads();
  uint16_t* ost = &SB[0][0];  // 256 rows x 64 cols
  {
    float inv = 1.0f / l;
    uint16_t* wst = ost + wid * 2048;
#pragma unroll
    for (int mo = 0; mo < 2; ++mo)
#pragma unroll
      for (int r = 0; r < 16; r += 2) {
        int hd = mo * 32 + (r & 3) + 8 * (r >> 2) + 4 * hi;
        uint32_t pk = pack2(acc[mo][r] * inv, acc[mo][r + 1] * inv);
        int col = hd ^ ((ql & 7) << 3);
        *(uint32_t*)&wst[ql * 64 + col] = pk;
      }
  }
  __syncthreads();
  {
    int row = tid >> 1, half = tid & 1;
    int r7 = row & 7;
    int b = bh >> 4, h = bh & 15;
    size_t g = (size_t)(b * T_ + q0 + row) * D_ + h * 64 + half * 32;
#pragma unroll
    for (int j2 = 0; j2 < 4; ++j2) {
      int cc = half * 4 + j2;
      uint4 val = *(const uint4*)&ost[row * 64 + (cc ^ r7) * 8];
      *(uint4*)&O[g + j2 * 8] = val;
    }
  }
}

// ---------------- launcher ----------------
extern "C" void kernel_launch(void* const* d_in, const int* in_sizes, int n_in,
                              void* d_out, int out_size, void* d_ws, size_t ws_size,
                              hipStream_t stream) {
  (void)in_sizes; (void)n_in; (void)out_size; (void)ws_size;
  const float* q  = (const float*)d_in[0];
  const float* k  = (const float*)d_in[1];
  const float* v  = (const float*)d_in[2];
  // d_in[3] = mask (causal; structure hardcoded)
  const float* Wq = (const float*)d_in[4];
  const float* Wk = (const float*)d_in[5];
  const float* Wv = (const float*)d_in[6];
  const float* Wo = (const float*)d_in[7];

  uint8_t* ws = (uint8_t*)d_ws;
  const size_t MB = 1u << 20;
  uint16_t* WQB = (uint16_t*)(ws + 0 * MB);
  uint16_t* WKB = (uint16_t*)(ws + 2 * MB);
  uint16_t* WVB = (uint16_t*)(ws + 4 * MB);
  uint16_t* WOB = (uint16_t*)(ws + 6 * MB);
  uint16_t* XQ  = (uint16_t*)(ws + 8 * MB);
  uint16_t* XK  = (uint16_t*)(ws + 24 * MB);
  uint16_t* XV  = (uint16_t*)(ws + 40 * MB);
  uint16_t* QH  = (uint16_t*)(ws + 56 * MB);
  uint16_t* KH  = (uint16_t*)(ws + 72 * MB);
  uint16_t* VT  = (uint16_t*)(ws + 88 * MB);
  uint16_t* AC  = (uint16_t*)(ws + 8 * MB);  // alias XQ (dead after QKV gemm)

  const int nBig = B_ * T_ * D_;   // 8388608
  cvt3<<<dim3(nBig / 2048, 3), 256, 0, stream>>>(q, k, v, XQ, XK, XV);
  cvtW<<<dim3(D_ * D_ / 2048, 4), 256, 0, stream>>>(Wq, Wk, Wv, Wo, WQB, WKB, WVB, WOB);

  // Q scale = HD^-0.5 * log2(e) -> softmax in exp2 domain
  const float qscale = 0.125f * 1.44269504088896340736f;

  // fused QKV projections: 3 x 512 blocks of 128x128
  gemmBR<<<dim3(1536), 256, 0, stream>>>(XQ, XK, XV, WQB, WKB, WVB,
                                         QH, KH, VT, 0, qscale);

  attn_fwd<<<dim3(T_ / 256 * 64), 512, 0, stream>>>(QH, KH, VT, AC);

  // output projection: 512 blocks, fp32 out
  gemmBR<<<dim3(512), 256, 0, stream>>>(AC, nullptr, nullptr,
                                        WOB, nullptr, nullptr,
                                        d_out, nullptr, nullptr, 3, 1.0f);
}

// Round 11
// 167.280 us; speedup vs baseline: 1.3879x; 1.3879x over previous
//
#include <hip/hip_runtime.h>
#include <stdint.h>

#define B_  4
#define T_  2048
#define D_  1024
#define H_  16
#define HD_ 64
#define KK_ 1024

typedef __bf16 bf16_t;
typedef __bf16 bf16x8 __attribute__((ext_vector_type(8)));
typedef float  f32x4  __attribute__((ext_vector_type(4)));
typedef float  f32x16 __attribute__((ext_vector_type(16)));

__device__ __forceinline__ uint16_t f2bf(float f) {
  uint32_t x = __float_as_uint(f);
  uint32_t r = (x + 0x7fffu + ((x >> 16) & 1u)) >> 16;
  return (uint16_t)r;
}

__device__ __forceinline__ uint32_t pack2(float a, float b) {
  return (uint32_t)f2bf(a) | ((uint32_t)f2bf(b) << 16);
}

__device__ __forceinline__ float exp2a(float x) {
  float r;
  asm("v_exp_f32 %0, %1" : "=v"(r) : "v"(x));
  return r;
}

__device__ __forceinline__ uint32_t cvtpk(float a, float b) {
  uint32_t r;
  asm("v_cvt_pk_bf16_f32 %0, %1, %2" : "=v"(r) : "v"(a), "v"(b));
  return r;
}

__device__ __forceinline__ void plswap(uint32_t& a, uint32_t& b) {
  asm("v_permlane32_swap_b32 %0, %1" : "+v"(a), "+v"(b));
}

// async 16B global->LDS; lds dst is wave-uniform base (+lane*16 by HW)
__device__ __forceinline__ void gll16(const void* g, void* l) {
  __builtin_amdgcn_global_load_lds(
      (const __attribute__((address_space(1))) void*)g,
      (__attribute__((address_space(3))) void*)l, 16, 0, 0);
}

// ---------------- fp32 -> bf16 conversion (single launch for all 7 arrays) ----------------
// blocks 0..12287: q,k,v (4096 each); blocks 12288..14335: Wq,Wk,Wv,Wo (512 each)
__global__ __launch_bounds__(256)
void cvtAll(const float* __restrict__ q, const float* __restrict__ k,
            const float* __restrict__ v, const float* __restrict__ wq,
            const float* __restrict__ wk, const float* __restrict__ wv,
            const float* __restrict__ wo, uint16_t* __restrict__ dq,
            uint16_t* __restrict__ dk, uint16_t* __restrict__ dv,
            uint16_t* __restrict__ dwq, uint16_t* __restrict__ dwk,
            uint16_t* __restrict__ dwv, uint16_t* __restrict__ dwo) {
  const float* in;
  uint16_t* out;
  int off;
  int b = blockIdx.x;
  if (b < 12288) {
    int which = b >> 12;          // /4096
    off = b & 4095;
    in = which == 0 ? q : (which == 1 ? k : v);
    out = which == 0 ? dq : (which == 1 ? dk : dv);
  } else {
    int j = b - 12288;
    int which = j >> 9;           // /512
    off = j & 511;
    in = which == 0 ? wq : (which == 1 ? wk : (which == 2 ? wv : wo));
    out = which == 0 ? dwq : (which == 1 ? dwk : (which == 2 ? dwv : dwo));
  }
  int i = (off * 256 + threadIdx.x) * 8;
  float4 a = *(const float4*)(in + i);
  float4 c = *(const float4*)(in + i + 4);
  uint4 u;
  u.x = pack2(a.x, a.y);
  u.y = pack2(a.z, a.w);
  u.z = pack2(c.x, c.y);
  u.w = pack2(c.z, c.w);
  *(uint4*)(out + i) = u;
}

// ---------------- deep-pipelined GEMM: C = A[M,K] @ W[N,K]^T (R5 config) ----------------
// BM=128, BN=256, BK=64, 8 waves (2M x 4N), 64x64 per wave.
// 3 LDS buffers (144KB), stage-2-ahead, counted vmcnt(6), setprio.
// mode 0: Q -> bf16 [B,H,T,64] scaled; 1: K same; 2: V -> [B,H,64,T]; 3: fp32.
__global__ __launch_bounds__(512, 2)
void gemm8(const uint16_t* __restrict__ a0, const uint16_t* __restrict__ a1,
           const uint16_t* __restrict__ a2, const uint16_t* __restrict__ w0,
           const uint16_t* __restrict__ w1, const uint16_t* __restrict__ w2,
           void* __restrict__ o0, void* __restrict__ o1, void* __restrict__ o2,
           int mode_base, float scale0) {
  __shared__ __align__(16) uint16_t Ab[3][128 * 64];  // 48 KB
  __shared__ __align__(16) uint16_t Bb[3][256 * 64];  // 96 KB

  const int nwg = gridDim.x;
  const int bid = blockIdx.x;
  const int cpx = nwg >> 3;                       // nwg % 8 == 0
  const int swz = (bid & 7) * cpx + (bid >> 3);   // XCD-contiguous chunks
  const int g = swz >> 8;                         // 256 blocks per gemm
  const int r = swz & 255;
  const int mt = r >> 2, nt = r & 3;
  const int m0 = mt * 128, n0 = nt * 256;

  const uint16_t* A = g == 0 ? a0 : (g == 1 ? a1 : a2);
  const uint16_t* W = g == 0 ? w0 : (g == 1 ? w1 : w2);
  void* Out = g == 0 ? o0 : (g == 1 ? o1 : o2);
  const int mode = mode_base + g;
  const float scale = (mode == 0) ? scale0 : 1.0f;

  const int tid = threadIdx.x;
  const int wid = tid >> 6, lane = tid & 63;
  const int fr = lane & 15, fq = lane >> 4;
  const int wm = wid >> 2, wn = wid & 3;
  const int srow = lane >> 3, c8 = lane & 7;  // staging row-in-group / chunk

  f32x4 acc[4][4];
#pragma unroll
  for (int i = 0; i < 4; ++i)
#pragma unroll
    for (int j = 0; j < 4; ++j) acc[i][j] = (f32x4){0.f, 0.f, 0.f, 0.f};

  const int NT = KK_ / 64;  // 16 tiles

  // Rows are 64 elems (8 chunks of 8). LDS[row][j] = src[row][j ^ (row&7)].
#define STAGE(bi, t)                                                          \
  do {                                                                        \
    _Pragma("unroll")                                                         \
    for (int c = 0; c < 2; ++c) {                                             \
      int row = c * 64 + wid * 8 + srow;                                      \
      int sw = (c8 ^ (row & 7)) << 3;                                         \
      gll16(A + (size_t)(m0 + row) * KK_ + (t) * 64 + sw,                     \
            &Ab[bi][c * 4096 + wid * 512]);                                   \
    }                                                                         \
    _Pragma("unroll")                                                         \
    for (int c = 0; c < 4; ++c) {                                             \
      int row = c * 64 + wid * 8 + srow;                                      \
      int sw = (c8 ^ (row & 7)) << 3;                                         \
      gll16(W + (size_t)(n0 + row) * KK_ + (t) * 64 + sw,                     \
            &Bb[bi][c * 4096 + wid * 512]);                                   \
    }                                                                         \
  } while (0)

  // prologue: stage tiles 0,1; wait tile 0 (6 = tile 1's loads still flying)
  STAGE(0, 0);
  STAGE(1, 1);
  asm volatile("s_waitcnt vmcnt(6)" ::: "memory");
  __builtin_amdgcn_s_barrier();

  int cur = 0;
  for (int t = 0; t < NT; ++t) {
    const uint16_t* Ac = &Ab[cur][0];
    const uint16_t* Bc = &Bb[cur][0];
    // k-slice 0 frags
    bf16x8 af0[4], bf0[4];
#pragma unroll
    for (int i = 0; i < 4; ++i) {
      int ra = wm * 64 + i * 16 + fr;
      af0[i] = *(const bf16x8*)&Ac[ra * 64 + ((fq ^ (ra & 7)) << 3)];
      int rb = wn * 64 + i * 16 + fr;
      bf0[i] = *(const bf16x8*)&Bc[rb * 64 + ((fq ^ (rb & 7)) << 3)];
    }
    // prefetch tile t+2
    if (t + 2 < NT) {
      int nb = cur + 2; if (nb >= 3) nb -= 3;
      STAGE(nb, t + 2);
    }
    // k-slice 1 frags
    bf16x8 af1[4], bf1[4];
#pragma unroll
    for (int i = 0; i < 4; ++i) {
      int ra = wm * 64 + i * 16 + fr;
      af1[i] = *(const bf16x8*)&Ac[ra * 64 + (((4 + fq) ^ (ra & 7)) << 3)];
      int rb = wn * 64 + i * 16 + fr;
      bf1[i] = *(const bf16x8*)&Bc[rb * 64 + (((4 + fq) ^ (rb & 7)) << 3)];
    }
    __builtin_amdgcn_s_setprio(1);
#pragma unroll
    for (int mf = 0; mf < 4; ++mf)
#pragma unroll
      for (int nf = 0; nf < 4; ++nf)
        acc[mf][nf] = __builtin_amdgcn_mfma_f32_16x16x32_bf16(af0[mf], bf0[nf],
                                                              acc[mf][nf], 0, 0, 0);
#pragma unroll
    for (int mf = 0; mf < 4; ++mf)
#pragma unroll
      for (int nf = 0; nf < 4; ++nf)
        acc[mf][nf] = __builtin_amdgcn_mfma_f32_16x16x32_bf16(af1[mf], bf1[nf],
                                                              acc[mf][nf], 0, 0, 0);
    __builtin_amdgcn_s_setprio(0);
    if (t + 1 < NT) {
      if (t + 2 < NT) {
        asm volatile("s_waitcnt vmcnt(6)" ::: "memory");  // t+1 landed, t+2 flying
      } else {
        asm volatile("s_waitcnt vmcnt(0)" ::: "memory");  // tail
      }
      __builtin_amdgcn_s_barrier();
    }
    ++cur; if (cur == 3) cur = 0;
  }
#undef STAGE

  // epilogue
#pragma unroll
  for (int mf = 0; mf < 4; ++mf) {
#pragma unroll
    for (int nf = 0; nf < 4; ++nf) {
      int m = m0 + wm * 64 + mf * 16 + fq * 4;
      int n = n0 + wn * 64 + nf * 16 + fr;
      if (mode == 2) {
        int b = m >> 11, t = m & (T_ - 1);
        int h = n >> 6, hd = n & 63;
        uint2 pk;
        pk.x = pack2(acc[mf][nf][0], acc[mf][nf][1]);
        pk.y = pack2(acc[mf][nf][2], acc[mf][nf][3]);
        uint16_t* dst = (uint16_t*)Out + ((((size_t)b * H_ + h) * HD_ + hd) * T_ + t);
        *(uint2*)dst = pk;
      } else if (mode == 3) {
#pragma unroll
        for (int rr = 0; rr < 4; ++rr)
          ((float*)Out)[(size_t)(m + rr) * D_ + n] = acc[mf][nf][rr];
      } else {
#pragma unroll
        for (int rr = 0; rr < 4; ++rr) {
          int mm = m + rr;
          int b = mm >> 11, t = mm & (T_ - 1);
          int h = n >> 6, hd = n & 63;
          ((uint16_t*)Out)[((((size_t)b * H_ + h) * T_ + t) << 6) + hd] =
              f2bf(acc[mf][nf][rr] * scale);
        }
      }
    }
  }
}

// ---------------- flash attention (causal), 8 waves x 32 q, 32x32 swapped ----------------
// Triple-buffered K/V, counted vmcnt(2), longest-first grid (R5 config).
// Qh,Kh: [B,H,T,64] bf16 (Q pre-scaled by 0.125*log2e). Vt: [B,H,64,T] bf16.
__global__ __launch_bounds__(512)
void attn_fwd(const uint16_t* __restrict__ Qh, const uint16_t* __restrict__ Kh,
              const uint16_t* __restrict__ Vt, uint16_t* __restrict__ O) {
  // SB[0..2] = K triple buffer, SB[3..5] = V triple buffer (48 KB).
  __shared__ __align__(16) uint16_t SB[6][64 * 64];

  const int tid = threadIdx.x, wid = tid >> 6, lane = tid & 63;
  const int ql = lane & 31, hi = lane >> 5;
  const int bid = blockIdx.x;
  const int qb = (T_ / 256 - 1) - (bid >> 6);  // longest blocks first
  const int bh = bid & 63;
  const int q0 = qb * 256;
  const int wq0 = q0 + wid * 32;  // this wave's first q row
  const size_t hoff = (size_t)bh * T_ * HD_;
  const uint16_t* Qp = Qh + hoff;
  const uint16_t* Kp = Kh + hoff;
  const uint16_t* Vp = Vt + hoff;

  // Q fragments (B-operand): lane owns q-row (wq0+ql); k = hd = ks*16 + hi*8 + j
  bf16x8 qf[4];
  {
    const uint16_t* qrow = Qp + (size_t)(wq0 + ql) * 64 + hi * 8;
#pragma unroll
    for (int ks = 0; ks < 4; ++ks) qf[ks] = *(const bf16x8*)(qrow + ks * 16);
  }

  float m = -1e30f, l = 0.f;
  f32x16 acc[2];  // O^T: row = hd = mo*32 + (r&3)+8*(r>>2)+4*hi, col = q = ql
#pragma unroll
  for (int mo = 0; mo < 2; ++mo)
#pragma unroll
    for (int r = 0; r < 16; ++r) acc[mo][r] = 0.f;

  const int ntiles = 4 * qb + 4;

#define STAGE(buf, t)                                                        \
  do {                                                                       \
    int row = wid * 8 + (lane >> 3);                                         \
    int sw = ((lane & 7) ^ (row & 7)) << 3;                                  \
    gll16(Kp + (size_t)((t) * 64 + row) * 64 + sw, &SB[buf][wid * 512]);     \
    gll16(Vp + (size_t)row * T_ + (t) * 64 + sw, &SB[3 + (buf)][wid * 512]); \
  } while (0)

  STAGE(0, 0);
  if (ntiles > 1) STAGE(1, 1);
  asm volatile("s_waitcnt vmcnt(2)" ::: "memory");
  __builtin_amdgcn_s_barrier();

  int cur = 0;
  for (int it = 0; it < ntiles; ++it) {
    if (it + 2 < ntiles) {
      int nb = cur + 2; if (nb >= 3) nb -= 3;
      STAGE(nb, it + 2);
    }

    if (it * 64 <= wq0 + 31) {  // wave active unless whole tile above diagonal
      // S^T = K @ Q : col = q (lane-local), rows = kv
      f32x16 st[2];
#pragma unroll
      for (int mm = 0; mm < 2; ++mm)
#pragma unroll
        for (int r = 0; r < 16; ++r) st[mm][r] = 0.f;
#pragma unroll
      for (int ks = 0; ks < 4; ++ks) {
#pragma unroll
        for (int mm = 0; mm < 2; ++mm) {
          int row = mm * 32 + ql;
          int ch = (ks * 2 + hi) ^ (row & 7);
          bf16x8 kf = *(const bf16x8*)&SB[cur][row * 64 + ch * 8];
          st[mm] = __builtin_amdgcn_mfma_f32_32x32x16_bf16(kf, qf[ks], st[mm], 0, 0, 0);
        }
      }

      // causal mask (diagonal-straddling tiles only)
      if (it * 64 + 63 > wq0) {
        int qg = wq0 + ql;
#pragma unroll
        for (int mm = 0; mm < 2; ++mm)
#pragma unroll
          for (int r = 0; r < 16; ++r) {
            int kv = it * 64 + mm * 32 + (r & 3) + 8 * (r >> 2) + 4 * hi;
            if (kv > qg) st[mm][r] = -1e30f;
          }
      }

      // row max: 32 in-lane + pair lane
      float pm = st[0][0];
#pragma unroll
      for (int r = 1; r < 16; ++r) pm = fmaxf(pm, st[0][r]);
#pragma unroll
      for (int r = 0; r < 16; ++r) pm = fmaxf(pm, st[1][r]);
      pm = fmaxf(pm, __shfl_xor(pm, 32));

      // defer-max rescale (THR = 8 in log2 domain)
      if (__any(pm > m + 8.f)) {
        float mn = fmaxf(m, pm);
        float sf = exp2a(m - mn);
        m = mn;
        l *= sf;
#pragma unroll
        for (int mo = 0; mo < 2; ++mo)
#pragma unroll
          for (int r = 0; r < 16; ++r) acc[mo][r] *= sf;
      }

      // P = exp2(S - m), row sum
      float rs = 0.f;
#pragma unroll
      for (int mm = 0; mm < 2; ++mm)
#pragma unroll
        for (int r = 0; r < 16; ++r) {
          float p = exp2a(st[mm][r] - m);
          st[mm][r] = p;
          rs += p;
        }
      rs += __shfl_xor(rs, 32);
      l += rs;

      // P -> bf16 B-frags in-register (cvt_pk + permlane32_swap)
      bf16x8 pf[4];
#pragma unroll
      for (int mm = 0; mm < 2; ++mm)
#pragma unroll
        for (int g = 0; g < 2; ++g) {
          uint32_t a1 = cvtpk(st[mm][8 * g + 0], st[mm][8 * g + 1]);
          uint32_t a2 = cvtpk(st[mm][8 * g + 2], st[mm][8 * g + 3]);
          uint32_t b1 = cvtpk(st[mm][8 * g + 4], st[mm][8 * g + 5]);
          uint32_t b2 = cvtpk(st[mm][8 * g + 6], st[mm][8 * g + 7]);
          plswap(a1, b1);
          plswap(a2, b2);
          union { uint32_t w[4]; bf16x8 v; } u;
          u.w[0] = a1; u.w[1] = a2; u.w[2] = b1; u.w[3] = b2;
          pf[mm * 2 + g] = u.v;
        }

      // O^T += V^T @ P^T
#pragma unroll
      for (int ks = 0; ks < 4; ++ks) {
#pragma unroll
        for (int mo = 0; mo < 2; ++mo) {
          int row = mo * 32 + ql;
          int ch = (ks * 2 + hi) ^ (row & 7);
          bf16x8 vf = *(const bf16x8*)&SB[3 + cur][row * 64 + ch * 8];
          acc[mo] = __builtin_amdgcn_mfma_f32_32x32x16_bf16(vf, pf[ks], acc[mo], 0, 0, 0);
        }
      }
    }

    if (it + 1 < ntiles) {
      if (it + 2 < ntiles) {
        asm volatile("s_waitcnt vmcnt(2)" ::: "memory");  // it+1 landed, it+2 flying
      } else {
        asm volatile("s_waitcnt vmcnt(0)" ::: "memory");  // tail
      }
      __builtin_amdgcn_s_barrier();
    }
    ++cur; if (cur == 3) cur = 0;
  }
#undef STAGE

  // epilogue: O^T -> LDS (transpose, swizzled) -> coalesced global store
  __syncthreads();
  uint16_t* ost = &SB[0][0];  // 256 rows x 64 cols
  {
    float inv = 1.0f / l;
    uint16_t* wst = ost + wid * 2048;
#pragma unroll
    for (int mo = 0; mo < 2; ++mo)
#pragma unroll
      for (int r = 0; r < 16; r += 2) {
        int hd = mo * 32 + (r & 3) + 8 * (r >> 2) + 4 * hi;
        uint32_t pk = pack2(acc[mo][r] * inv, acc[mo][r + 1] * inv);
        int col = hd ^ ((ql & 7) << 3);
        *(uint32_t*)&wst[ql * 64 + col] = pk;
      }
  }
  __syncthreads();
  {
    int row = tid >> 1, half = tid & 1;
    int r7 = row & 7;
    int b = bh >> 4, h = bh & 15;
    size_t g = (size_t)(b * T_ + q0 + row) * D_ + h * 64 + half * 32;
#pragma unroll
    for (int j2 = 0; j2 < 4; ++j2) {
      int cc = half * 4 + j2;
      uint4 val = *(const uint4*)&ost[row * 64 + (cc ^ r7) * 8];
      *(uint4*)&O[g + j2 * 8] = val;
    }
  }
}

// ---------------- launcher ----------------
extern "C" void kernel_launch(void* const* d_in, const int* in_sizes, int n_in,
                              void* d_out, int out_size, void* d_ws, size_t ws_size,
                              hipStream_t stream) {
  (void)in_sizes; (void)n_in; (void)out_size; (void)ws_size;
  const float* q  = (const float*)d_in[0];
  const float* k  = (const float*)d_in[1];
  const float* v  = (const float*)d_in[2];
  // d_in[3] = mask (causal; structure hardcoded)
  const float* Wq = (const float*)d_in[4];
  const float* Wk = (const float*)d_in[5];
  const float* Wv = (const float*)d_in[6];
  const float* Wo = (const float*)d_in[7];

  uint8_t* ws = (uint8_t*)d_ws;
  const size_t MB = 1u << 20;
  uint16_t* WQB = (uint16_t*)(ws + 0 * MB);
  uint16_t* WKB = (uint16_t*)(ws + 2 * MB);
  uint16_t* WVB = (uint16_t*)(ws + 4 * MB);
  uint16_t* WOB = (uint16_t*)(ws + 6 * MB);
  uint16_t* XQ  = (uint16_t*)(ws + 8 * MB);
  uint16_t* XK  = (uint16_t*)(ws + 24 * MB);
  uint16_t* XV  = (uint16_t*)(ws + 40 * MB);
  uint16_t* QH  = (uint16_t*)(ws + 56 * MB);
  uint16_t* KH  = (uint16_t*)(ws + 72 * MB);
  uint16_t* VT  = (uint16_t*)(ws + 88 * MB);
  uint16_t* AC  = (uint16_t*)(ws + 8 * MB);  // alias XQ (dead after QKV gemm)

  // all fp32 -> bf16 conversions in one launch (12288 big + 2048 weight blocks)
  cvtAll<<<dim3(14336), 256, 0, stream>>>(q, k, v, Wq, Wk, Wv, Wo,
                                          XQ, XK, XV, WQB, WKB, WVB, WOB);

  // Q scale = HD^-0.5 * log2(e) -> softmax in exp2 domain
  const float qscale = 0.125f * 1.44269504088896340736f;

  // fused QKV projections: 3 x 256 blocks
  gemm8<<<dim3(768), 512, 0, stream>>>(XQ, XK, XV, WQB, WKB, WVB,
                                       QH, KH, VT, 0, qscale);

  attn_fwd<<<dim3(T_ / 256 * 64), 512, 0, stream>>>(QH, KH, VT, AC);

  // output projection: 256 blocks, fp32 out
  gemm8<<<dim3(256), 512, 0, stream>>>(AC, nullptr, nullptr, WOB, nullptr, nullptr,
                                       d_out, nullptr, nullptr, 3, 1.0f);
}

// Round 12
// 164.119 us; speedup vs baseline: 1.4146x; 1.0193x over previous
//
#include <hip/hip_runtime.h>
#include <stdint.h>

#define B_  4
#define T_  2048
#define D_  1024
#define H_  16
#define HD_ 64
#define KK_ 1024

typedef __bf16 bf16_t;
typedef __bf16 bf16x8 __attribute__((ext_vector_type(8)));
typedef float  f32x4  __attribute__((ext_vector_type(4)));
typedef float  f32x16 __attribute__((ext_vector_type(16)));

__device__ __forceinline__ uint16_t f2bf(float f) {
  uint32_t x = __float_as_uint(f);
  uint32_t r = (x + 0x7fffu + ((x >> 16) & 1u)) >> 16;
  return (uint16_t)r;
}

__device__ __forceinline__ uint32_t pack2(float a, float b) {
  return (uint32_t)f2bf(a) | ((uint32_t)f2bf(b) << 16);
}

__device__ __forceinline__ float exp2a(float x) {
  float r;
  asm("v_exp_f32 %0, %1" : "=v"(r) : "v"(x));
  return r;
}

__device__ __forceinline__ uint32_t cvtpk(float a, float b) {
  uint32_t r;
  asm("v_cvt_pk_bf16_f32 %0, %1, %2" : "=v"(r) : "v"(a), "v"(b));
  return r;
}

__device__ __forceinline__ void plswap(uint32_t& a, uint32_t& b) {
  asm("v_permlane32_swap_b32 %0, %1" : "+v"(a), "+v"(b));
}

// async 16B global->LDS; lds dst is wave-uniform base (+lane*16 by HW)
__device__ __forceinline__ void gll16(const void* g, void* l) {
  __builtin_amdgcn_global_load_lds(
      (const __attribute__((address_space(1))) void*)g,
      (__attribute__((address_space(3))) void*)l, 16, 0, 0);
}

// ---------------- fp32 -> bf16 conversion (weights only) ----------------
__global__ __launch_bounds__(256) void cvtW(const float* __restrict__ s0,
                                            const float* __restrict__ s1,
                                            const float* __restrict__ s2,
                                            const float* __restrict__ s3,
                                            uint16_t* __restrict__ d0,
                                            uint16_t* __restrict__ d1,
                                            uint16_t* __restrict__ d2,
                                            uint16_t* __restrict__ d3) {
  const float* in = blockIdx.y == 0 ? s0 : (blockIdx.y == 1 ? s1 :
                    (blockIdx.y == 2 ? s2 : s3));
  uint16_t* out = blockIdx.y == 0 ? d0 : (blockIdx.y == 1 ? d1 :
                  (blockIdx.y == 2 ? d2 : d3));
  int i = (blockIdx.x * 256 + threadIdx.x) * 8;
  float4 a = *(const float4*)(in + i);
  float4 b = *(const float4*)(in + i + 4);
  uint4 u;
  u.x = pack2(a.x, a.y);
  u.y = pack2(a.z, a.w);
  u.z = pack2(b.x, b.y);
  u.w = pack2(b.z, b.w);
  *(uint4*)(out + i) = u;
}

// ---------------- deep-pipelined GEMM: C = A[M,K] @ W[N,K]^T (R5 config) ----------------
// BM=128, BN=256, BK=64, 8 waves (2M x 4N), 64x64 per wave.
// 3 LDS buffers (144KB), stage-2-ahead, counted vmcnt, setprio.
// AF32: A fp32 in HBM, 2-tile-distance reg pipeline (tile t issues A(t+2) loads,
// PINNED by sched_barrier(0); end of tile t converts+writes A(t+1), one full
// tile after issue -> latency hidden; compiler auto-vmcnts the reg deps).
// mode 0: Q -> bf16 [B,H,T,64] scaled; 1: K same; 2: V -> [B,H,64,T]; 3: fp32.
template <bool AF32>
__global__ __launch_bounds__(512, 2)
void gemm8(const void* __restrict__ a0, const void* __restrict__ a1,
           const void* __restrict__ a2, const uint16_t* __restrict__ w0,
           const uint16_t* __restrict__ w1, const uint16_t* __restrict__ w2,
           void* __restrict__ o0, void* __restrict__ o1, void* __restrict__ o2,
           int mode_base, float scale0) {
  __shared__ __align__(16) uint16_t Ab[3][128 * 64];  // 48 KB
  __shared__ __align__(16) uint16_t Bb[3][256 * 64];  // 96 KB

  const int nwg = gridDim.x;
  const int bid = blockIdx.x;
  const int cpx = nwg >> 3;                       // nwg % 8 == 0
  const int swz = (bid & 7) * cpx + (bid >> 3);   // XCD-contiguous chunks
  const int g = swz >> 8;                         // 256 blocks per gemm
  const int r = swz & 255;
  const int mt = r >> 2, nt = r & 3;
  const int m0 = mt * 128, n0 = nt * 256;

  const void* A = g == 0 ? a0 : (g == 1 ? a1 : a2);
  const uint16_t* W = g == 0 ? w0 : (g == 1 ? w1 : w2);
  void* Out = g == 0 ? o0 : (g == 1 ? o1 : o2);
  const int mode = mode_base + g;
  const float scale = (mode == 0) ? scale0 : 1.0f;
  const float* A32 = (const float*)A;
  const uint16_t* A16 = (const uint16_t*)A;

  const int tid = threadIdx.x;
  const int wid = tid >> 6, lane = tid & 63;
  const int fr = lane & 15, fq = lane >> 4;
  const int wm = wid >> 2, wn = wid & 3;
  const int srow = lane >> 3, c8 = lane & 7;  // staging row-in-group / chunk

  f32x4 acc[4][4];
#pragma unroll
  for (int i = 0; i < 4; ++i)
#pragma unroll
    for (int j = 0; j < 4; ++j) acc[i][j] = (f32x4){0.f, 0.f, 0.f, 0.f};

  const int NT = KK_ / 64;  // 16 tiles (even -> reg-set parity static)
  float4 axA[4], axB[4];    // two in-flight fp32 A reg sets (AF32 only)

  // Rows are 64 elems (8 chunks of 8). LDS[row][j] = src[row][j ^ (row&7)].
#define ALOAD(ax, t)                                                          \
  do {                                                                        \
    _Pragma("unroll")                                                         \
    for (int c = 0; c < 2; ++c) {                                             \
      int row = c * 64 + wid * 8 + srow;                                      \
      int sw = (c8 ^ (row & 7)) << 3;                                         \
      const float* src = A32 + (size_t)(m0 + row) * KK_ + (t) * 64 + sw;      \
      ax[c * 2] = *(const float4*)src;                                        \
      ax[c * 2 + 1] = *(const float4*)(src + 4);                              \
    }                                                                         \
  } while (0)

  // same per-lane LDS dest as gll16's HW dest (lane*8 elems = srow*64 + c8*8)
#define AWRITE(bi, ax)                                                        \
  do {                                                                        \
    _Pragma("unroll")                                                         \
    for (int c = 0; c < 2; ++c) {                                             \
      uint4 u;                                                                \
      u.x = cvtpk(ax[c * 2].x, ax[c * 2].y);                                  \
      u.y = cvtpk(ax[c * 2].z, ax[c * 2].w);                                  \
      u.z = cvtpk(ax[c * 2 + 1].x, ax[c * 2 + 1].y);                          \
      u.w = cvtpk(ax[c * 2 + 1].z, ax[c * 2 + 1].w);                          \
      *(uint4*)&Ab[bi][c * 4096 + wid * 512 + srow * 64 + c8 * 8] = u;        \
    }                                                                         \
  } while (0)

#define STAGEA16(bi, t)                                                       \
  do {                                                                        \
    _Pragma("unroll")                                                         \
    for (int c = 0; c < 2; ++c) {                                             \
      int row = c * 64 + wid * 8 + srow;                                      \
      int sw = (c8 ^ (row & 7)) << 3;                                         \
      gll16(A16 + (size_t)(m0 + row) * KK_ + (t) * 64 + sw,                   \
            &Ab[bi][c * 4096 + wid * 512]);                                   \
    }                                                                         \
  } while (0)

#define STAGEB(bi, t)                                                         \
  do {                                                                        \
    _Pragma("unroll")                                                         \
    for (int c = 0; c < 4; ++c) {                                             \
      int row = c * 64 + wid * 8 + srow;                                      \
      int sw = (c8 ^ (row & 7)) << 3;                                         \
      gll16(W + (size_t)(n0 + row) * KK_ + (t) * 64 + sw,                     \
            &Bb[bi][c * 4096 + wid * 512]);                                   \
    }                                                                         \
  } while (0)

  // ---- prologue ----
  if (AF32) {
    ALOAD(axA, 0);                          // A0 -> regs
    __builtin_amdgcn_sched_barrier(0);      // pin the loads here
    STAGEB(0, 0);
    AWRITE(0, axA);                         // auto vmcnt for axA
    ALOAD(axA, 1);                          // A1 -> regs (written at end of t=0)
    __builtin_amdgcn_sched_barrier(0);
    STAGEB(1, 1);
    asm volatile("s_waitcnt vmcnt(8)" ::: "memory");   // B0 landed; A1+B1 flying
    asm volatile("s_waitcnt lgkmcnt(0)" ::: "memory"); // A0 ds_writes done
  } else {
    STAGEA16(0, 0);
    STAGEB(0, 0);
    STAGEA16(1, 1);
    STAGEB(1, 1);
    asm volatile("s_waitcnt vmcnt(6)" ::: "memory");   // tile0 done; tile1 flying
  }
  __builtin_amdgcn_s_barrier();

  // BODY(t): k-slice0 frag reads; issue t+2 staging (pinned); k-slice1 reads;
  // MFMAs; AF32: AWRITE A(t+1) (regs 1 tile old); counted seam; barrier.
#define BODY(t, axU, axL)                                                     \
  do {                                                                        \
    const uint16_t* Ac = &Ab[cur][0];                                         \
    const uint16_t* Bc = &Bb[cur][0];                                         \
    int nb = cur + 2; if (nb >= 3) nb -= 3;                                   \
    bf16x8 af0[4], bf0[4], af1[4], bf1[4];                                    \
    _Pragma("unroll")                                                         \
    for (int i = 0; i < 4; ++i) {                                             \
      int ra = wm * 64 + i * 16 + fr;                                         \
      af0[i] = *(const bf16x8*)&Ac[ra * 64 + ((fq ^ (ra & 7)) << 3)];         \
      int rb = wn * 64 + i * 16 + fr;                                         \
      bf0[i] = *(const bf16x8*)&Bc[rb * 64 + ((fq ^ (rb & 7)) << 3)];         \
    }                                                                         \
    if ((t) + 2 < NT) {                                                       \
      if (AF32) {                                                             \
        ALOAD(axL, (t) + 2);                                                  \
        __builtin_amdgcn_sched_barrier(0); /* pin loads: issue NOW */         \
      } else {                                                                \
        STAGEA16(nb, (t) + 2);                                                \
      }                                                                       \
      STAGEB(nb, (t) + 2);                                                    \
    }                                                                         \
    _Pragma("unroll")                                                         \
    for (int i = 0; i < 4; ++i) {                                             \
      int ra = wm * 64 + i * 16 + fr;                                         \
      af1[i] = *(const bf16x8*)&Ac[ra * 64 + (((4 + fq) ^ (ra & 7)) << 3)];   \
      int rb = wn * 64 + i * 16 + fr;                                         \
      bf1[i] = *(const bf16x8*)&Bc[rb * 64 + (((4 + fq) ^ (rb & 7)) << 3)];   \
    }                                                                         \
    __builtin_amdgcn_s_setprio(1);                                            \
    _Pragma("unroll")                                                         \
    for (int mf = 0; mf < 4; ++mf)                                            \
      _Pragma("unroll")                                                       \
      for (int nf = 0; nf < 4; ++nf)                                          \
        acc[mf][nf] = __builtin_amdgcn_mfma_f32_16x16x32_bf16(                \
            af0[mf], bf0[nf], acc[mf][nf], 0, 0, 0);                          \
    _Pragma("unroll")                                                         \
    for (int mf = 0; mf < 4; ++mf)                                            \
      _Pragma("unroll")                                                       \
      for (int nf = 0; nf < 4; ++nf)                                          \
        acc[mf][nf] = __builtin_amdgcn_mfma_f32_16x16x32_bf16(                \
            af1[mf], bf1[nf], acc[mf][nf], 0, 0, 0);                          \
    __builtin_amdgcn_s_setprio(0);                                            \
    if ((t) + 1 < NT) {                                                       \
      int wb = cur + 1; if (wb >= 3) wb -= 3;                                 \
      if (AF32) AWRITE(wb, axU); /* A(t+1) -> LDS; regs 1 tile old */         \
      if ((t) + 2 < NT) {                                                     \
        asm volatile("s_waitcnt vmcnt(%0)" ::"i"(AF32 ? 8 : 6) : "memory");   \
      } else {                                                                \
        asm volatile("s_waitcnt vmcnt(0)" ::: "memory");                      \
      }                                                                       \
      if (AF32) asm volatile("s_waitcnt lgkmcnt(0)" ::: "memory");            \
      __builtin_amdgcn_s_barrier();                                           \
    }                                                                         \
    ++cur; if (cur == 3) cur = 0;                                             \
  } while (0)

  int cur = 0;
  for (int tt = 0; tt < NT; tt += 2) {
    BODY(tt, axA, axB);
    BODY(tt + 1, axB, axA);
  }
#undef BODY
#undef ALOAD
#undef AWRITE
#undef STAGEA16
#undef STAGEB

  // epilogue
#pragma unroll
  for (int mf = 0; mf < 4; ++mf) {
#pragma unroll
    for (int nf = 0; nf < 4; ++nf) {
      int m = m0 + wm * 64 + mf * 16 + fq * 4;
      int n = n0 + wn * 64 + nf * 16 + fr;
      if (mode == 2) {
        int b = m >> 11, t = m & (T_ - 1);
        int h = n >> 6, hd = n & 63;
        uint2 pk;
        pk.x = pack2(acc[mf][nf][0], acc[mf][nf][1]);
        pk.y = pack2(acc[mf][nf][2], acc[mf][nf][3]);
        uint16_t* dst = (uint16_t*)Out + ((((size_t)b * H_ + h) * HD_ + hd) * T_ + t);
        *(uint2*)dst = pk;
      } else if (mode == 3) {
#pragma unroll
        for (int rr = 0; rr < 4; ++rr)
          ((float*)Out)[(size_t)(m + rr) * D_ + n] = acc[mf][nf][rr];
      } else {
#pragma unroll
        for (int rr = 0; rr < 4; ++rr) {
          int mm = m + rr;
          int b = mm >> 11, t = mm & (T_ - 1);
          int h = n >> 6, hd = n & 63;
          ((uint16_t*)Out)[((((size_t)b * H_ + h) * T_ + t) << 6) + hd] =
              f2bf(acc[mf][nf][rr] * scale);
        }
      }
    }
  }
}

// ---------------- flash attention (causal), 8 waves x 32 q, 32x32 swapped ----------------
// Triple-buffered K/V, counted vmcnt(2), longest-first grid (R5 config).
// Qh,Kh: [B,H,T,64] bf16 (Q pre-scaled by 0.125*log2e). Vt: [B,H,64,T] bf16.
__global__ __launch_bounds__(512)
void attn_fwd(const uint16_t* __restrict__ Qh, const uint16_t* __restrict__ Kh,
              const uint16_t* __restrict__ Vt, uint16_t* __restrict__ O) {
  // SB[0..2] = K triple buffer, SB[3..5] = V triple buffer (48 KB).
  __shared__ __align__(16) uint16_t SB[6][64 * 64];

  const int tid = threadIdx.x, wid = tid >> 6, lane = tid & 63;
  const int ql = lane & 31, hi = lane >> 5;
  const int bid = blockIdx.x;
  const int qb = (T_ / 256 - 1) - (bid >> 6);  // longest blocks first
  const int bh = bid & 63;
  const int q0 = qb * 256;
  const int wq0 = q0 + wid * 32;  // this wave's first q row
  const size_t hoff = (size_t)bh * T_ * HD_;
  const uint16_t* Qp = Qh + hoff;
  const uint16_t* Kp = Kh + hoff;
  const uint16_t* Vp = Vt + hoff;

  // Q fragments (B-operand): lane owns q-row (wq0+ql); k = hd = ks*16 + hi*8 + j
  bf16x8 qf[4];
  {
    const uint16_t* qrow = Qp + (size_t)(wq0 + ql) * 64 + hi * 8;
#pragma unroll
    for (int ks = 0; ks < 4; ++ks) qf[ks] = *(const bf16x8*)(qrow + ks * 16);
  }

  float m = -1e30f, l = 0.f;
  f32x16 acc[2];  // O^T: row = hd = mo*32 + (r&3)+8*(r>>2)+4*hi, col = q = ql
#pragma unroll
  for (int mo = 0; mo < 2; ++mo)
#pragma unroll
    for (int r = 0; r < 16; ++r) acc[mo][r] = 0.f;

  const int ntiles = 4 * qb + 4;

#define STAGE(buf, t)                                                        \
  do {                                                                       \
    int row = wid * 8 + (lane >> 3);                                         \
    int sw = ((lane & 7) ^ (row & 7)) << 3;                                  \
    gll16(Kp + (size_t)((t) * 64 + row) * 64 + sw, &SB[buf][wid * 512]);     \
    gll16(Vp + (size_t)row * T_ + (t) * 64 + sw, &SB[3 + (buf)][wid * 512]); \
  } while (0)

  STAGE(0, 0);
  if (ntiles > 1) STAGE(1, 1);
  asm volatile("s_waitcnt vmcnt(2)" ::: "memory");
  __builtin_amdgcn_s_barrier();

  int cur = 0;
  for (int it = 0; it < ntiles; ++it) {
    if (it + 2 < ntiles) {
      int nb = cur + 2; if (nb >= 3) nb -= 3;
      STAGE(nb, it + 2);
    }

    if (it * 64 <= wq0 + 31) {  // wave active unless whole tile above diagonal
      // S^T = K @ Q : col = q (lane-local), rows = kv
      f32x16 st[2];
#pragma unroll
      for (int mm = 0; mm < 2; ++mm)
#pragma unroll
        for (int r = 0; r < 16; ++r) st[mm][r] = 0.f;
#pragma unroll
      for (int ks = 0; ks < 4; ++ks) {
#pragma unroll
        for (int mm = 0; mm < 2; ++mm) {
          int row = mm * 32 + ql;
          int ch = (ks * 2 + hi) ^ (row & 7);
          bf16x8 kf = *(const bf16x8*)&SB[cur][row * 64 + ch * 8];
          st[mm] = __builtin_amdgcn_mfma_f32_32x32x16_bf16(kf, qf[ks], st[mm], 0, 0, 0);
        }
      }

      // causal mask (diagonal-straddling tiles only)
      if (it * 64 + 63 > wq0) {
        int qg = wq0 + ql;
#pragma unroll
        for (int mm = 0; mm < 2; ++mm)
#pragma unroll
          for (int r = 0; r < 16; ++r) {
            int kv = it * 64 + mm * 32 + (r & 3) + 8 * (r >> 2) + 4 * hi;
            if (kv > qg) st[mm][r] = -1e30f;
          }
      }

      // row max: 32 in-lane + pair lane
      float pm = st[0][0];
#pragma unroll
      for (int r = 1; r < 16; ++r) pm = fmaxf(pm, st[0][r]);
#pragma unroll
      for (int r = 0; r < 16; ++r) pm = fmaxf(pm, st[1][r]);
      pm = fmaxf(pm, __shfl_xor(pm, 32));

      // defer-max rescale (THR = 8 in log2 domain)
      if (__any(pm > m + 8.f)) {
        float mn = fmaxf(m, pm);
        float sf = exp2a(m - mn);
        m = mn;
        l *= sf;
#pragma unroll
        for (int mo = 0; mo < 2; ++mo)
#pragma unroll
          for (int r = 0; r < 16; ++r) acc[mo][r] *= sf;
      }

      // P = exp2(S - m), row sum
      float rs = 0.f;
#pragma unroll
      for (int mm = 0; mm < 2; ++mm)
#pragma unroll
        for (int r = 0; r < 16; ++r) {
          float p = exp2a(st[mm][r] - m);
          st[mm][r] = p;
          rs += p;
        }
      rs += __shfl_xor(rs, 32);
      l += rs;

      // P -> bf16 B-frags in-register (cvt_pk + permlane32_swap)
      bf16x8 pf[4];
#pragma unroll
      for (int mm = 0; mm < 2; ++mm)
#pragma unroll
        for (int g = 0; g < 2; ++g) {
          uint32_t a1 = cvtpk(st[mm][8 * g + 0], st[mm][8 * g + 1]);
          uint32_t a2 = cvtpk(st[mm][8 * g + 2], st[mm][8 * g + 3]);
          uint32_t b1 = cvtpk(st[mm][8 * g + 4], st[mm][8 * g + 5]);
          uint32_t b2 = cvtpk(st[mm][8 * g + 6], st[mm][8 * g + 7]);
          plswap(a1, b1);
          plswap(a2, b2);
          union { uint32_t w[4]; bf16x8 v; } u;
          u.w[0] = a1; u.w[1] = a2; u.w[2] = b1; u.w[3] = b2;
          pf[mm * 2 + g] = u.v;
        }

      // O^T += V^T @ P^T
#pragma unroll
      for (int ks = 0; ks < 4; ++ks) {
#pragma unroll
        for (int mo = 0; mo < 2; ++mo) {
          int row = mo * 32 + ql;
          int ch = (ks * 2 + hi) ^ (row & 7);
          bf16x8 vf = *(const bf16x8*)&SB[3 + cur][row * 64 + ch * 8];
          acc[mo] = __builtin_amdgcn_mfma_f32_32x32x16_bf16(vf, pf[ks], acc[mo], 0, 0, 0);
        }
      }
    }

    if (it + 1 < ntiles) {
      if (it + 2 < ntiles) {
        asm volatile("s_waitcnt vmcnt(2)" ::: "memory");  // it+1 landed, it+2 flying
      } else {
        asm volatile("s_waitcnt vmcnt(0)" ::: "memory");  // tail
      }
      __builtin_amdgcn_s_barrier();
    }
    ++cur; if (cur == 3) cur = 0;
  }
#undef STAGE

  // epilogue: O^T -> LDS (transpose, swizzled) -> coalesced global store
  __syncthreads();
  uint16_t* ost = &SB[0][0];  // 256 rows x 64 cols
  {
    float inv = 1.0f / l;
    uint16_t* wst = ost + wid * 2048;
#pragma unroll
    for (int mo = 0; mo < 2; ++mo)
#pragma unroll
      for (int r = 0; r < 16; r += 2) {
        int hd = mo * 32 + (r & 3) + 8 * (r >> 2) + 4 * hi;
        uint32_t pk = pack2(acc[mo][r] * inv, acc[mo][r + 1] * inv);
        int col = hd ^ ((ql & 7) << 3);
        *(uint32_t*)&wst[ql * 64 + col] = pk;
      }
  }
  __syncthreads();
  {
    int row = tid >> 1, half = tid & 1;
    int r7 = row & 7;
    int b = bh >> 4, h = bh & 15;
    size_t g = (size_t)(b * T_ + q0 + row) * D_ + h * 64 + half * 32;
#pragma unroll
    for (int j2 = 0; j2 < 4; ++j2) {
      int cc = half * 4 + j2;
      uint4 val = *(const uint4*)&ost[row * 64 + (cc ^ r7) * 8];
      *(uint4*)&O[g + j2 * 8] = val;
    }
  }
}

// ---------------- launcher ----------------
extern "C" void kernel_launch(void* const* d_in, const int* in_sizes, int n_in,
                              void* d_out, int out_size, void* d_ws, size_t ws_size,
                              hipStream_t stream) {
  (void)in_sizes; (void)n_in; (void)out_size; (void)ws_size;
  const float* q  = (const float*)d_in[0];
  const float* k  = (const float*)d_in[1];
  const float* v  = (const float*)d_in[2];
  // d_in[3] = mask (causal; structure hardcoded)
  const float* Wq = (const float*)d_in[4];
  const float* Wk = (const float*)d_in[5];
  const float* Wv = (const float*)d_in[6];
  const float* Wo = (const float*)d_in[7];

  uint8_t* ws = (uint8_t*)d_ws;
  const size_t MB = 1u << 20;
  uint16_t* WQB = (uint16_t*)(ws + 0 * MB);
  uint16_t* WKB = (uint16_t*)(ws + 2 * MB);
  uint16_t* WVB = (uint16_t*)(ws + 4 * MB);
  uint16_t* WOB = (uint16_t*)(ws + 6 * MB);
  uint16_t* QH  = (uint16_t*)(ws + 56 * MB);
  uint16_t* KH  = (uint16_t*)(ws + 72 * MB);
  uint16_t* VT  = (uint16_t*)(ws + 88 * MB);
  uint16_t* AC  = (uint16_t*)(ws + 8 * MB);

  // weights fp32 -> bf16 (tiny)
  cvtW<<<dim3(D_ * D_ / 2048, 4), 256, 0, stream>>>(Wq, Wk, Wv, Wo, WQB, WKB, WVB, WOB);

  // Q scale = HD^-0.5 * log2(e) -> softmax in exp2 domain
  const float qscale = 0.125f * 1.44269504088896340736f;

  // fused QKV projections (fp32 A converted in-kernel): 3 x 256 blocks
  gemm8<true><<<dim3(768), 512, 0, stream>>>(q, k, v, WQB, WKB, WVB,
                                             QH, KH, VT, 0, qscale);

  attn_fwd<<<dim3(T_ / 256 * 64), 512, 0, stream>>>(QH, KH, VT, AC);

  // output projection (bf16 A from attention): 256 blocks, fp32 out
  gemm8<false><<<dim3(256), 512, 0, stream>>>(AC, nullptr, nullptr,
                                              WOB, nullptr, nullptr,
                                              d_out, nullptr, nullptr, 3, 1.0f);
}